// Round 1
// baseline (4921.544 us; speedup 1.0000x reference)
//
#include <hip/hip_runtime.h>

typedef unsigned short u16;
typedef __attribute__((ext_vector_type(4))) float f32x4;
typedef __attribute__((ext_vector_type(8))) __bf16 bf16x8;

#define SEQ   4096
#define HID   4096
#define HID3  12288

__device__ __forceinline__ float bf2f(u16 u){
  union { unsigned int i; float f; } v; v.i = ((unsigned int)u) << 16; return v.f;
}
__device__ __forceinline__ u16 f2bf(float f){
  union { float f; unsigned int i; } v; v.f = f;
  unsigned int r = (v.i + 0x7FFFu + ((v.i >> 16) & 1u)) >> 16;
  return (u16)r;
}
__device__ __forceinline__ float slope_of(int h){
  const float factor = 1.0f - 1.0f/(31.0f + 1e-5f) + 1e-5f;
  return exp2f(-0.25f * (float)(h + 1)) * factor;
}

// ---------------- fp32 -> bf16 convert (vectorized) ----------------
__global__ __launch_bounds__(256) void cvt_kernel(const float* __restrict__ in,
                                                  u16* __restrict__ out, long n){
  long i = ((long)blockIdx.x * 256 + threadIdx.x) * 4;
  long stride = (long)gridDim.x * 1024;
  for (; i < n; i += stride){
    float4 v = *(const float4*)(in + i);
    ushort4 o;
    o.x = f2bf(v.x); o.y = f2bf(v.y); o.z = f2bf(v.z); o.w = f2bf(v.w);
    *(ushort4*)(out + i) = o;
  }
}

// ---------------- bf16 GEMM, C[M][N] = A[M][K] * B[N][K]^T (m97 structure) ----
__device__ __forceinline__ void gload_lds16(const u16* g, u16* l){
  __builtin_amdgcn_global_load_lds((const __attribute__((address_space(1))) void*)g,
                                   (__attribute__((address_space(3))) void*)l, 16, 0, 0);
}

// EPI: 0 = silu -> bf16 ; 1 = sigmoid * Aux -> bf16 ; 2 = raw -> fp32
template<int EPI>
__global__ __launch_bounds__(256) void gemm_bt(
    const u16* __restrict__ A, const u16* __restrict__ B, void* __restrict__ C,
    const u16* __restrict__ Aux, int M, int N, int K)
{
  __shared__ u16 As[128 * 32];
  __shared__ u16 Bs[128 * 32];
  int t = threadIdx.x;
  int nbn = N >> 7;
  int bm = blockIdx.x / nbn, bn = blockIdx.x % nbn;
  int w = t >> 6, l = t & 63;
  int lr = l & 15, lk = l >> 4;
  int wrow = (w >> 1) << 6, wcol = (w & 1) << 6;
  f32x4 acc[4][4] = {};

  int lin0 = w * 512 + l * 8;          // element offset covered by this lane, issue 0
  int row0 = lin0 >> 5, col0 = lin0 & 31;
  int lin1 = lin0 + 2048;              // issue 1
  int row1 = lin1 >> 5, col1 = lin1 & 31;
  const u16* Abase = A + (long)(bm * 128) * K;
  const u16* Bbase = B + (long)(bn * 128) * K;
  u16* AsW0 = As + w * 512;            // wave-uniform LDS bases
  u16* AsW1 = As + w * 512 + 2048;
  u16* BsW0 = Bs + w * 512;
  u16* BsW1 = Bs + w * 512 + 2048;

  for (int k0 = 0; k0 < K; k0 += 32){
    gload_lds16(Abase + (long)row0 * K + k0 + col0, AsW0);
    gload_lds16(Abase + (long)row1 * K + k0 + col1, AsW1);
    gload_lds16(Bbase + (long)row0 * K + k0 + col0, BsW0);
    gload_lds16(Bbase + (long)row1 * K + k0 + col1, BsW1);
    __syncthreads();
    bf16x8 af[4], bfr[4];
#pragma unroll
    for (int r = 0; r < 4; ++r){
      af[r]  = __builtin_bit_cast(bf16x8, *(const uint4*)&As[(wrow + r*16 + lr)*32 + lk*8]);
      bfr[r] = __builtin_bit_cast(bf16x8, *(const uint4*)&Bs[(wcol + r*16 + lr)*32 + lk*8]);
    }
#pragma unroll
    for (int i = 0; i < 4; ++i)
#pragma unroll
      for (int j = 0; j < 4; ++j)
        acc[i][j] = __builtin_amdgcn_mfma_f32_16x16x32_bf16(af[i], bfr[j], acc[i][j], 0, 0, 0);
    __syncthreads();
  }

  long crow = (long)bm * 128 + wrow + (l >> 4) * 4;
  long ccol = (long)bn * 128 + wcol + lr;
#pragma unroll
  for (int i = 0; i < 4; ++i)
#pragma unroll
    for (int j = 0; j < 4; ++j)
#pragma unroll
      for (int r = 0; r < 4; ++r){
        long row = crow + i * 16 + r;
        long col = ccol + j * 16;
        float x = acc[i][j][r];
        if (EPI == 0){
          ((u16*)C)[row * N + col] = f2bf(x / (1.0f + __expf(-x)));
        } else if (EPI == 1){
          float g = 1.0f / (1.0f + __expf(-x));
          ((u16*)C)[row * N + col] = f2bf(g * bf2f(Aux[row * N + col]));
        } else {
          ((float*)C)[row * N + col] = x;
        }
      }
}

// ---------------- attention phase 1: contribT[e][d] = sum_n v[n][e]*k[n][d]*kdec[n] ----
__global__ __launch_bounds__(256) void attn_contrib(
    const u16* __restrict__ qkv, float* __restrict__ ct)
{
  __shared__ u16 kb[256 * 128];
  __shared__ u16 vb[256 * 128];
  __shared__ float kdec[256];
  int wg = blockIdx.x;
  int bh = wg >> 4, blk = wg & 15;
  int b = bh >> 5, h = bh & 31;
  int t = threadIdx.x;
  float slope = slope_of(h);
  kdec[t] = __expf(-slope * (float)(255 - t));
  const u16* kg = qkv + ((long)(b * SEQ + blk * 256)) * HID3 + h * 384 + 128;
  const u16* vg = kg + 128;
#pragma unroll
  for (int i = 0; i < 16; ++i){
    int chunk = t + i * 256;
    int row = chunk >> 4, c8 = (chunk & 15) << 3;
    *(uint4*)&kb[row * 128 + c8] = *(const uint4*)&kg[(long)row * HID3 + c8];
    *(uint4*)&vb[row * 128 + c8] = *(const uint4*)&vg[(long)row * HID3 + c8];
  }
  __syncthreads();
  int e0 = (t >> 4) << 3, d0 = (t & 15) << 3;
  float acc[8][8];
#pragma unroll
  for (int i = 0; i < 8; ++i)
#pragma unroll
    for (int j = 0; j < 8; ++j) acc[i][j] = 0.f;
  for (int n = 0; n < 256; ++n){
    float kd = kdec[n];
    uint4 vv = *(const uint4*)&vb[n * 128 + e0];
    uint4 kk = *(const uint4*)&kb[n * 128 + d0];
    const u16* vs = (const u16*)&vv;
    const u16* ks = (const u16*)&kk;
    float ve[8], kf[8];
#pragma unroll
    for (int x = 0; x < 8; ++x){ ve[x] = bf2f(vs[x]); kf[x] = bf2f(ks[x]) * kd; }
#pragma unroll
    for (int i = 0; i < 8; ++i)
#pragma unroll
      for (int j = 0; j < 8; ++j) acc[i][j] += ve[i] * kf[j];
  }
  float* out = ct + (long)wg * 16384;
#pragma unroll
  for (int i = 0; i < 8; ++i){
    *(float4*)&out[(e0 + i) * 128 + d0]     = make_float4(acc[i][0], acc[i][1], acc[i][2], acc[i][3]);
    *(float4*)&out[(e0 + i) * 128 + d0 + 4] = make_float4(acc[i][4], acc[i][5], acc[i][6], acc[i][7]);
  }
}

// ---------------- attention phase 2: in-place decayed prefix scan over blocks ----
__global__ __launch_bounds__(256) void attn_scan(float* __restrict__ st)
{
  int bh = blockIdx.x, t = threadIdx.x;
  float bdec = __expf(-slope_of(bh & 31) * 256.0f);
  float cur[64];
#pragma unroll
  for (int i = 0; i < 64; ++i) cur[i] = 0.f;
  float* base = st + (long)bh * 16 * 16384;
  for (int blkI = 0; blkI < 16; ++blkI){
    float* p = base + (long)blkI * 16384;
#pragma unroll
    for (int i = 0; i < 64; ++i){
      float c = p[t + i * 256];
      p[t + i * 256] = cur[i];           // state used BY this block (pre-update)
      cur[i] = cur[i] * bdec + c;
    }
  }
}

// ---------------- attention phase 3: intra (causal decayed) + inter ----
__global__ __launch_bounds__(512) void attn_main(
    const u16* __restrict__ qkv, const float* __restrict__ stT, u16* __restrict__ attn)
{
  __shared__ u16 kb[256 * 128];
  __shared__ u16 vb[256 * 128];
  __shared__ float sb[256 * 16];   // scores tile; later reused as state chunk [16][128]
  int wg = blockIdx.x;
  int bh = wg >> 4, blk = wg & 15;
  int b = bh >> 5, h = bh & 31;
  int t = threadIdx.x;
  float slope = slope_of(h);
  const u16* qg = qkv + ((long)(b * SEQ + blk * 256)) * HID3 + h * 384;
  const u16* kg = qg + 128;
  const u16* vg = qg + 256;
#pragma unroll
  for (int i = 0; i < 8; ++i){
    int chunk = t + i * 512;
    int row = chunk >> 4, c8 = (chunk & 15) << 3;
    *(uint4*)&kb[row * 128 + c8] = *(const uint4*)&kg[(long)row * HID3 + c8];
    *(uint4*)&vb[row * 128 + c8] = *(const uint4*)&vg[(long)row * HID3 + c8];
  }
  int nA = t >> 1, mh = t & 1;
  uint4 qrow[16];
#pragma unroll
  for (int i = 0; i < 16; ++i) qrow[i] = *(const uint4*)&qg[(long)nA * HID3 + i * 8];
  __syncthreads();

  float accv[4][16];
#pragma unroll
  for (int r = 0; r < 4; ++r)
#pragma unroll
    for (int c = 0; c < 16; ++c) accv[r][c] = 0.f;
  int ng = t >> 3, eg = t & 7;
  int n0 = ng << 2, e0 = eg << 4;

  for (int mt = 0; mt < 16; ++mt){
    int mb = mt << 4;
    int mbase = mb + mh * 8;
    float s[8];
#pragma unroll
    for (int j = 0; j < 8; ++j) s[j] = 0.f;
    if (mbase <= nA){
#pragma unroll
      for (int dc = 0; dc < 16; ++dc){
        float qf[8];
        const u16* qu = (const u16*)&qrow[dc];
#pragma unroll
        for (int x = 0; x < 8; ++x) qf[x] = bf2f(qu[x]);
#pragma unroll
        for (int j = 0; j < 8; ++j){
          uint4 kv = *(const uint4*)&kb[(mbase + j) * 128 + dc * 8];
          const u16* k8 = (const u16*)&kv;
          float a0 = s[j];
#pragma unroll
          for (int x = 0; x < 8; ++x) a0 += qf[x] * bf2f(k8[x]);
          s[j] = a0;
        }
      }
#pragma unroll
      for (int j = 0; j < 8; ++j){
        int m = mbase + j;
        float dec = (m <= nA) ? __expf(-slope * (float)(nA - m)) : 0.f;
        s[j] *= dec;
      }
    }
#pragma unroll
    for (int j = 0; j < 8; ++j) sb[nA * 16 + mh * 8 + j] = s[j];
    __syncthreads();
    if (n0 + 3 >= mb){
#pragma unroll
      for (int m = 0; m < 16; ++m){
        float s0 = sb[(n0 + 0) * 16 + m], s1 = sb[(n0 + 1) * 16 + m];
        float s2 = sb[(n0 + 2) * 16 + m], s3 = sb[(n0 + 3) * 16 + m];
        uint4 v0 = *(const uint4*)&vb[(mb + m) * 128 + e0];
        uint4 v1 = *(const uint4*)&vb[(mb + m) * 128 + e0 + 8];
        const u16* va = (const u16*)&v0;
        const u16* vx = (const u16*)&v1;
        float vf[16];
#pragma unroll
        for (int x = 0; x < 8; ++x){ vf[x] = bf2f(va[x]); vf[8 + x] = bf2f(vx[x]); }
#pragma unroll
        for (int c = 0; c < 16; ++c){
          float vv = vf[c];
          accv[0][c] += s0 * vv; accv[1][c] += s1 * vv;
          accv[2][c] += s2 * vv; accv[3][c] += s3 * vv;
        }
      }
    }
    __syncthreads();
  }

  // inter: accv[r][e] += qdec[n] * sum_d q[n][d] * state[d][e]  (stT[e][d] = state[d][e])
  const float* stg = stT + (long)(bh * 16 + blk) * 16384;
  float* stl = sb;                    // [16][128]
  int se = t >> 2, sd0 = (t & 3) << 2;
  for (int dc = 0; dc < 8; ++dc){
    float4 sv = *(const float4*)&stg[(long)se * 128 + dc * 16 + sd0];
    stl[(sd0 + 0) * 128 + se] = sv.x;
    stl[(sd0 + 1) * 128 + se] = sv.y;
    stl[(sd0 + 2) * 128 + se] = sv.z;
    stl[(sd0 + 3) * 128 + se] = sv.w;
    __syncthreads();
#pragma unroll
    for (int r = 0; r < 4; ++r){
      int n = n0 + r;
      float qd = __expf(-slope * (float)(n + 1));
      uint4 q0 = *(const uint4*)&qg[(long)n * HID3 + dc * 16];
      uint4 q1 = *(const uint4*)&qg[(long)n * HID3 + dc * 16 + 8];
      const u16* qa = (const u16*)&q0;
      const u16* qb = (const u16*)&q1;
      float qf[16];
#pragma unroll
      for (int x = 0; x < 8; ++x){ qf[x] = bf2f(qa[x]) * qd; qf[8 + x] = bf2f(qb[x]) * qd; }
#pragma unroll
      for (int dp = 0; dp < 16; ++dp){
        float qv = qf[dp];
        const float* sp = &stl[dp * 128 + e0];
#pragma unroll
        for (int c = 0; c < 16; ++c) accv[r][c] += qv * sp[c];
      }
    }
    __syncthreads();
  }

  u16* arow = attn + ((long)(b * SEQ + blk * 256)) * HID + h * 128;
#pragma unroll
  for (int r = 0; r < 4; ++r){
    int n = n0 + r;
    alignas(16) u16 o[16];
#pragma unroll
    for (int c = 0; c < 16; ++c) o[c] = f2bf(accv[r][c]);
    *(uint4*)&arow[(long)n * HID + e0]     = *(const uint4*)&o[0];
    *(uint4*)&arow[(long)n * HID + e0 + 8] = *(const uint4*)&o[8];
  }
}

// ---------------- RMSNorm in-place on attn rows ----------------
__global__ __launch_bounds__(256) void rmsnorm_ip(u16* __restrict__ attn,
                                                  const float* __restrict__ nw)
{
  __shared__ float wsum[4];
  int row = blockIdx.x, t = threadIdx.x;
  u16* p = attn + (long)row * HID;
  uint4 v0 = *(const uint4*)&p[t * 8];
  uint4 v1 = *(const uint4*)&p[t * 8 + 2048];
  const u16* a0 = (const u16*)&v0;
  const u16* a1 = (const u16*)&v1;
  float f0[8], f1[8];
  float ss = 0.f;
#pragma unroll
  for (int x = 0; x < 8; ++x){
    f0[x] = bf2f(a0[x]); f1[x] = bf2f(a1[x]);
    ss += f0[x] * f0[x] + f1[x] * f1[x];
  }
#pragma unroll
  for (int off = 32; off > 0; off >>= 1) ss += __shfl_down(ss, off);
  if ((t & 63) == 0) wsum[t >> 6] = ss;
  __syncthreads();
  float rs = rsqrtf((wsum[0] + wsum[1] + wsum[2] + wsum[3]) * (1.0f / 4096.0f) + 1e-5f);
  alignas(16) u16 o0[8], o1[8];
#pragma unroll
  for (int x = 0; x < 8; ++x){
    o0[x] = f2bf(f0[x] * rs * nw[t * 8 + x]);
    o1[x] = f2bf(f1[x] * rs * nw[t * 8 + 2048 + x]);
  }
  *(uint4*)&p[t * 8]        = *(const uint4*)&o0[0];
  *(uint4*)&p[t * 8 + 2048] = *(const uint4*)&o1[0];
}

// ---------------- launch ----------------
extern "C" void kernel_launch(void* const* d_in, const int* in_sizes, int n_in,
                              void* d_out, int out_size, void* d_ws, size_t ws_size,
                              hipStream_t stream)
{
  const float* hidden = (const float*)d_in[0];
  const float* qkv_w  = (const float*)d_in[1];
  const float* out_w  = (const float*)d_in[2];   // NOTE: out_w is input 2
  const float* gate_w = (const float*)d_in[3];
  const float* norm_w = (const float*)d_in[4];
  char* ws = (char*)d_ws;
  const long SZ_X  = 67108864L;    // 8192*4096 bf16
  const long SZ_WQ = 100663296L;   // 12288*4096 bf16
  const long SZ_WG = 33554432L;    // 4096*4096 bf16
  const long SZ_WO = 33554432L;
  const long SZ_QA = 201326592L;   // 8192*12288 bf16
  const long SZ_AT = 67108864L;    // 8192*4096 bf16
  u16* Xb   = (u16*)(ws);
  u16* Wq   = (u16*)(ws + SZ_X);
  u16* Wg   = (u16*)(ws + SZ_X + SZ_WQ);
  u16* Wo   = (u16*)(ws + SZ_X + SZ_WQ + SZ_WG);
  u16* qact = (u16*)(ws + SZ_X + SZ_WQ + SZ_WG + SZ_WO);
  u16* attn = (u16*)(ws + SZ_X + SZ_WQ + SZ_WG + SZ_WO + SZ_QA);
  float* st  = (float*)Wq;    // 67MB states overlay qkv_w region (dead after K1)
  u16* gated = qact;          // gated overlays qkv activations (dead after attention)
  if (ws_size < (size_t)(SZ_X + SZ_WQ + SZ_WG + SZ_WO + SZ_QA + SZ_AT)) return;

  cvt_kernel<<<1024, 256, 0, stream>>>(hidden, Xb, 33554432L);
  cvt_kernel<<<1024, 256, 0, stream>>>(qkv_w,  Wq, 50331648L);
  cvt_kernel<<<1024, 256, 0, stream>>>(gate_w, Wg, 16777216L);
  cvt_kernel<<<1024, 256, 0, stream>>>(out_w,  Wo, 16777216L);

  gemm_bt<0><<<64 * 96, 256, 0, stream>>>(Xb, Wq, (void*)qact, nullptr, 8192, 12288, 4096);

  attn_contrib<<<1024, 256, 0, stream>>>(qact, st);
  attn_scan<<<64, 256, 0, stream>>>(st);
  attn_main<<<1024, 512, 0, stream>>>(qact, st, attn);
  rmsnorm_ip<<<8192, 256, 0, stream>>>(attn, norm_w);

  gemm_bt<1><<<64 * 32, 256, 0, stream>>>(Xb, Wg, (void*)gated, attn, 8192, 4096, 4096);
  gemm_bt<2><<<64 * 32, 256, 0, stream>>>(gated, Wo, d_out, nullptr, 8192, 4096, 4096);
}

// Round 2
// 2506.480 us; speedup vs baseline: 1.9635x; 1.9635x over previous
//
#include <hip/hip_runtime.h>

typedef unsigned short u16;
typedef __attribute__((ext_vector_type(4))) float f32x4;
typedef __attribute__((ext_vector_type(8))) __bf16 bf16x8;

#define SEQ   4096
#define HID   4096
#define HID3  12288

__device__ __forceinline__ float bf2f(u16 u){
  union { unsigned int i; float f; } v; v.i = ((unsigned int)u) << 16; return v.f;
}
__device__ __forceinline__ u16 f2bf(float f){
  union { float f; unsigned int i; } v; v.f = f;
  unsigned int r = (v.i + 0x7FFFu + ((v.i >> 16) & 1u)) >> 16;
  return (u16)r;
}
__device__ __forceinline__ float slope_of(int h){
  const float factor = 1.0f - 1.0f/(31.0f + 1e-5f) + 1e-5f;
  return exp2f(-0.25f * (float)(h + 1)) * factor;
}
__device__ __forceinline__ bf16x8 ld_bf8(const u16* p){
  return __builtin_bit_cast(bf16x8, *(const uint4*)p);
}

// ---------------- fp32 -> bf16 convert (vectorized) ----------------
__global__ __launch_bounds__(256) void cvt_kernel(const float* __restrict__ in,
                                                  u16* __restrict__ out, long n){
  long i = ((long)blockIdx.x * 256 + threadIdx.x) * 4;
  long stride = (long)gridDim.x * 1024;
  for (; i < n; i += stride){
    float4 v = *(const float4*)(in + i);
    ushort4 o;
    o.x = f2bf(v.x); o.y = f2bf(v.y); o.z = f2bf(v.z); o.w = f2bf(v.w);
    *(ushort4*)(out + i) = o;
  }
}

// ---------------- bf16 GEMM, C[M][N] = A[M][K] * B[N][K]^T (m97 structure) ----
__device__ __forceinline__ void gload_lds16(const u16* g, u16* l){
  __builtin_amdgcn_global_load_lds((const __attribute__((address_space(1))) void*)g,
                                   (__attribute__((address_space(3))) void*)l, 16, 0, 0);
}

// EPI: 0 = silu -> bf16 ; 1 = sigmoid * Aux -> bf16 ; 2 = raw -> fp32
template<int EPI>
__global__ __launch_bounds__(256) void gemm_bt(
    const u16* __restrict__ A, const u16* __restrict__ B, void* __restrict__ C,
    const u16* __restrict__ Aux, int M, int N, int K)
{
  __shared__ u16 As[128 * 32];
  __shared__ u16 Bs[128 * 32];
  int t = threadIdx.x;
  int nbn = N >> 7;
  int nwg = gridDim.x;
  int bid = blockIdx.x;
  int bswz = (bid & 7) * (nwg >> 3) + (bid >> 3);   // bijective XCD swizzle (nwg%8==0)
  int bm = bswz / nbn, bn = bswz % nbn;
  int w = t >> 6, l = t & 63;
  int lr = l & 15, lk = l >> 4;
  int wrow = (w >> 1) << 6, wcol = (w & 1) << 6;
  f32x4 acc[4][4] = {};

  int lin0 = w * 512 + l * 8;
  int row0 = lin0 >> 5, col0 = lin0 & 31;
  int lin1 = lin0 + 2048;
  int row1 = lin1 >> 5, col1 = lin1 & 31;
  const u16* Abase = A + (long)(bm * 128) * K;
  const u16* Bbase = B + (long)(bn * 128) * K;
  u16* AsW0 = As + w * 512;
  u16* AsW1 = As + w * 512 + 2048;
  u16* BsW0 = Bs + w * 512;
  u16* BsW1 = Bs + w * 512 + 2048;

  for (int k0 = 0; k0 < K; k0 += 32){
    gload_lds16(Abase + (long)row0 * K + k0 + col0, AsW0);
    gload_lds16(Abase + (long)row1 * K + k0 + col1, AsW1);
    gload_lds16(Bbase + (long)row0 * K + k0 + col0, BsW0);
    gload_lds16(Bbase + (long)row1 * K + k0 + col1, BsW1);
    __syncthreads();
    bf16x8 af[4], bfr[4];
#pragma unroll
    for (int r = 0; r < 4; ++r){
      af[r]  = ld_bf8(&As[(wrow + r*16 + lr)*32 + lk*8]);
      bfr[r] = ld_bf8(&Bs[(wcol + r*16 + lr)*32 + lk*8]);
    }
#pragma unroll
    for (int i = 0; i < 4; ++i)
#pragma unroll
      for (int j = 0; j < 4; ++j)
        acc[i][j] = __builtin_amdgcn_mfma_f32_16x16x32_bf16(af[i], bfr[j], acc[i][j], 0, 0, 0);
    __syncthreads();
  }

  long crow = (long)bm * 128 + wrow + (l >> 4) * 4;
  long ccol = (long)bn * 128 + wcol + lr;
#pragma unroll
  for (int i = 0; i < 4; ++i)
#pragma unroll
    for (int j = 0; j < 4; ++j)
#pragma unroll
      for (int r = 0; r < 4; ++r){
        long row = crow + i * 16 + r;
        long col = ccol + j * 16;
        float x = acc[i][j][r];
        if (EPI == 0){
          ((u16*)C)[row * N + col] = f2bf(x / (1.0f + __expf(-x)));
        } else if (EPI == 1){
          float g = 1.0f / (1.0f + __expf(-x));
          ((u16*)C)[row * N + col] = f2bf(g * bf2f(Aux[row * N + col]));
        } else {
          ((float*)C)[row * N + col] = x;
        }
      }
}

// ---------------- attention phase 1: contribT[e][d] = sum_n v[n][e]*k[n][d]*kdec[n] ----
__global__ __launch_bounds__(256) void attn_contrib(
    const u16* __restrict__ qkv, float* __restrict__ ct)
{
  __shared__ u16 kb[256 * 128];
  __shared__ u16 vb[256 * 128];
  __shared__ float kdec[256];
  int wg = blockIdx.x;
  int bh = wg >> 4, blk = wg & 15;
  int b = bh >> 5, h = bh & 31;
  int t = threadIdx.x;
  float slope = slope_of(h);
  kdec[t] = __expf(-slope * (float)(255 - t));
  const u16* kg = qkv + ((long)(b * SEQ + blk * 256)) * HID3 + h * 384 + 128;
  const u16* vg = kg + 128;
#pragma unroll
  for (int i = 0; i < 16; ++i){
    int chunk = t + i * 256;
    int row = chunk >> 4, c8 = (chunk & 15) << 3;
    *(uint4*)&kb[row * 128 + c8] = *(const uint4*)&kg[(long)row * HID3 + c8];
    *(uint4*)&vb[row * 128 + c8] = *(const uint4*)&vg[(long)row * HID3 + c8];
  }
  __syncthreads();
  int e0 = (t >> 4) << 3, d0 = (t & 15) << 3;
  float acc[8][8];
#pragma unroll
  for (int i = 0; i < 8; ++i)
#pragma unroll
    for (int j = 0; j < 8; ++j) acc[i][j] = 0.f;
  for (int n = 0; n < 256; ++n){
    float kd = kdec[n];
    uint4 vv = *(const uint4*)&vb[n * 128 + e0];
    uint4 kk = *(const uint4*)&kb[n * 128 + d0];
    const u16* vs = (const u16*)&vv;
    const u16* ks = (const u16*)&kk;
    float ve[8], kf[8];
#pragma unroll
    for (int x = 0; x < 8; ++x){ ve[x] = bf2f(vs[x]); kf[x] = bf2f(ks[x]) * kd; }
#pragma unroll
    for (int i = 0; i < 8; ++i)
#pragma unroll
      for (int j = 0; j < 8; ++j) acc[i][j] += ve[i] * kf[j];
  }
  float* out = ct + (long)wg * 16384;
#pragma unroll
  for (int i = 0; i < 8; ++i){
    *(float4*)&out[(e0 + i) * 128 + d0]     = make_float4(acc[i][0], acc[i][1], acc[i][2], acc[i][3]);
    *(float4*)&out[(e0 + i) * 128 + d0 + 4] = make_float4(acc[i][4], acc[i][5], acc[i][6], acc[i][7]);
  }
}

// ---------------- attention phase 2: decayed prefix scan; emits bf16 pre-state ----
__global__ __launch_bounds__(256) void attn_scan(const float* __restrict__ ct,
                                                 u16* __restrict__ stTb)
{
  int bh = blockIdx.x, t = threadIdx.x;
  float bdec = __expf(-slope_of(bh & 31) * 256.0f);
  float cur[64];
#pragma unroll
  for (int i = 0; i < 64; ++i) cur[i] = 0.f;
  const float* base = ct + (long)bh * 16 * 16384;
  u16* ob = stTb + (long)bh * 16 * 16384;
  for (int blkI = 0; blkI < 16; ++blkI){
    const float* p = base + (long)blkI * 16384;
    u16* o = ob + (long)blkI * 16384;
#pragma unroll
    for (int i = 0; i < 64; ++i){
      o[t + i * 256] = f2bf(cur[i]);         // state used BY this block (pre-update)
      cur[i] = cur[i] * bdec + p[t + i * 256];
    }
  }
}

// ---------------- attention phase 3 (MFMA): intra (causal decay) + inter ----
__global__ __launch_bounds__(512) void attn_mfma(
    const u16* __restrict__ qkv, const u16* __restrict__ stTb, u16* __restrict__ attn)
{
  __shared__ u16 Ks[256 * 130];     // K rows [m][d], stride 130 (odd-dword pad)
  __shared__ u16 VTs[128 * 258];    // V^T rows [e][m], stride 258
  __shared__ u16 Ps[4][64 * 34];    // per n-rowpair: P[64 n][32 m], stride 34
  int wg = blockIdx.x;
  int bh = wg >> 4, blk = wg & 15;
  int b = bh >> 5, h = bh & 31;
  int t = threadIdx.x;
  int w = t >> 6, l = t & 63, lr = l & 15, lk = l >> 4;
  int r = w >> 1, c = w & 1;        // wave grid: 4 n-blocks x 2 e-blocks
  float slope = slope_of(h);
  const u16* qg = qkv + ((long)(b * SEQ + blk * 256)) * HID3 + h * 384;
  const u16* kg = qg + 128;
  const u16* vg = qg + 256;

  // stage K (row-major) and V^T (transposed, scalar writes)
#pragma unroll
  for (int i = 0; i < 8; ++i){
    int chunk = t + i * 512;
    int row = chunk >> 4, c8 = (chunk & 15) << 3;
    *(uint4*)&Ks[row * 130 + c8] = *(const uint4*)&kg[(long)row * HID3 + c8];
    uint4 vv = *(const uint4*)&vg[(long)row * HID3 + c8];
    const u16* vs = (const u16*)&vv;
#pragma unroll
    for (int x = 0; x < 8; ++x) VTs[(c8 + x) * 258 + row] = vs[x];
  }
  // Q fragments: rows r*64+fn*16+lr, k-chunks kc*32+lk*8  (64B-coalesced)
  bf16x8 qa[4][4];
#pragma unroll
  for (int fn = 0; fn < 4; ++fn)
#pragma unroll
    for (int kc = 0; kc < 4; ++kc)
      qa[fn][kc] = ld_bf8(&qg[(long)(r * 64 + fn * 16 + lr) * HID3 + kc * 32 + lk * 8]);
  f32x4 acc[4][4] = {};
  __syncthreads();

  int mtmax = 2 * r + 1;            // causal: wave r needs m-tiles 0..2r+1
  for (int mt = 0; mt < 8; ++mt){
    if (mt <= mtmax){
      // S^ (64n x 16m slice, this wave's c-half): QK^T over d=128
      f32x4 S[4] = {};
      int mrow = mt * 32 + c * 16 + lr;
      bf16x8 kb[4];
#pragma unroll
      for (int kc = 0; kc < 4; ++kc)
        kb[kc] = ld_bf8(&Ks[mrow * 130 + kc * 32 + lk * 8]);
#pragma unroll
      for (int fn = 0; fn < 4; ++fn)
#pragma unroll
        for (int kc = 0; kc < 4; ++kc)
          S[fn] = __builtin_amdgcn_mfma_f32_16x16x32_bf16(qa[fn][kc], kb[kc], S[fn], 0, 0, 0);
      // decay mask + write P (acc layout: col m = lane&15, row n = lk*4+reg)
      int m = mt * 32 + c * 16 + lr;
#pragma unroll
      for (int fn = 0; fn < 4; ++fn)
#pragma unroll
        for (int reg = 0; reg < 4; ++reg){
          int n = r * 64 + fn * 16 + lk * 4 + reg;
          float dv = (n >= m) ? __expf(-slope * (float)(n - m)) : 0.f;
          Ps[r][(fn * 16 + lk * 4 + reg) * 34 + c * 16 + lr] = f2bf(S[fn][reg] * dv);
        }
    }
    __syncthreads();
    if (mt <= mtmax){
      bf16x8 pa[4], vb[4];
#pragma unroll
      for (int fn = 0; fn < 4; ++fn)
        pa[fn] = ld_bf8(&Ps[r][(fn * 16 + lr) * 34 + lk * 8]);
#pragma unroll
      for (int fe = 0; fe < 4; ++fe)
        vb[fe] = ld_bf8(&VTs[(c * 64 + fe * 16 + lr) * 258 + mt * 32 + lk * 8]);
#pragma unroll
      for (int fn = 0; fn < 4; ++fn)
#pragma unroll
        for (int fe = 0; fe < 4; ++fe)
          acc[fn][fe] = __builtin_amdgcn_mfma_f32_16x16x32_bf16(pa[fn], vb[fe], acc[fn][fe], 0, 0, 0);
    }
    __syncthreads();
  }

  // inter: acc[n][e] += sum_d (q*qdec)[n][d] * stT[e][d]
#pragma unroll
  for (int fn = 0; fn < 4; ++fn){
    int n = r * 64 + fn * 16 + lr;
    float qd = __expf(-slope * (float)(n + 1));
#pragma unroll
    for (int kc = 0; kc < 4; ++kc){
      union { bf16x8 v; u16 u[8]; } uu; uu.v = qa[fn][kc];
#pragma unroll
      for (int x = 0; x < 8; ++x) uu.u[x] = f2bf(bf2f(uu.u[x]) * qd);
      qa[fn][kc] = uu.v;
    }
  }
  const u16* sg = stTb + (long)(bh * 16 + blk) * 16384;
#pragma unroll
  for (int kc = 0; kc < 4; ++kc){
    bf16x8 sb2[4];
#pragma unroll
    for (int fe = 0; fe < 4; ++fe)
      sb2[fe] = ld_bf8(&sg[(c * 64 + fe * 16 + lr) * 128 + kc * 32 + lk * 8]);
#pragma unroll
    for (int fn = 0; fn < 4; ++fn)
#pragma unroll
      for (int fe = 0; fe < 4; ++fe)
        acc[fn][fe] = __builtin_amdgcn_mfma_f32_16x16x32_bf16(qa[fn][kc], sb2[fe], acc[fn][fe], 0, 0, 0);
  }

  u16* arow = attn + ((long)(b * SEQ + blk * 256)) * HID + h * 128;
#pragma unroll
  for (int fn = 0; fn < 4; ++fn)
#pragma unroll
    for (int fe = 0; fe < 4; ++fe)
#pragma unroll
      for (int reg = 0; reg < 4; ++reg){
        int n = r * 64 + fn * 16 + lk * 4 + reg;
        int col = c * 64 + fe * 16 + lr;
        arow[(long)n * HID + col] = f2bf(acc[fn][fe][reg]);
      }
}

// ---------------- RMSNorm in-place on attn rows ----------------
__global__ __launch_bounds__(256) void rmsnorm_ip(u16* __restrict__ attn,
                                                  const float* __restrict__ nw)
{
  __shared__ float wsum[4];
  int row = blockIdx.x, t = threadIdx.x;
  u16* p = attn + (long)row * HID;
  uint4 v0 = *(const uint4*)&p[t * 8];
  uint4 v1 = *(const uint4*)&p[t * 8 + 2048];
  const u16* a0 = (const u16*)&v0;
  const u16* a1 = (const u16*)&v1;
  float f0[8], f1[8];
  float ss = 0.f;
#pragma unroll
  for (int x = 0; x < 8; ++x){
    f0[x] = bf2f(a0[x]); f1[x] = bf2f(a1[x]);
    ss += f0[x] * f0[x] + f1[x] * f1[x];
  }
#pragma unroll
  for (int off = 32; off > 0; off >>= 1) ss += __shfl_down(ss, off);
  if ((t & 63) == 0) wsum[t >> 6] = ss;
  __syncthreads();
  float rs = rsqrtf((wsum[0] + wsum[1] + wsum[2] + wsum[3]) * (1.0f / 4096.0f) + 1e-5f);
  alignas(16) u16 o0[8], o1[8];
#pragma unroll
  for (int x = 0; x < 8; ++x){
    o0[x] = f2bf(f0[x] * rs * nw[t * 8 + x]);
    o1[x] = f2bf(f1[x] * rs * nw[t * 8 + 2048 + x]);
  }
  *(uint4*)&p[t * 8]        = *(const uint4*)&o0[0];
  *(uint4*)&p[t * 8 + 2048] = *(const uint4*)&o1[0];
}

// ---------------- launch ----------------
extern "C" void kernel_launch(void* const* d_in, const int* in_sizes, int n_in,
                              void* d_out, int out_size, void* d_ws, size_t ws_size,
                              hipStream_t stream)
{
  const float* hidden = (const float*)d_in[0];
  const float* qkv_w  = (const float*)d_in[1];
  const float* out_w  = (const float*)d_in[2];
  const float* gate_w = (const float*)d_in[3];
  const float* norm_w = (const float*)d_in[4];
  char* ws = (char*)d_ws;
  const long SZ_X  = 67108864L;    // 8192*4096 bf16
  const long SZ_WQ = 100663296L;   // 12288*4096 bf16
  const long SZ_WG = 33554432L;
  const long SZ_WO = 33554432L;
  const long SZ_QA = 201326592L;   // 8192*12288 bf16
  const long SZ_AT = 67108864L;    // 8192*4096 bf16
  u16* Xb   = (u16*)(ws);
  u16* Wq   = (u16*)(ws + SZ_X);
  u16* Wg   = (u16*)(ws + SZ_X + SZ_WQ);
  u16* Wo   = (u16*)(ws + SZ_X + SZ_WQ + SZ_WG);
  u16* qact = (u16*)(ws + SZ_X + SZ_WQ + SZ_WG + SZ_WO);
  u16* attn = (u16*)(ws + SZ_X + SZ_WQ + SZ_WG + SZ_WO + SZ_QA);
  // overlays in the (dead after gemm<0>) Wq region: fp32 contribs (67.1MB) + bf16 states (33.5MB)
  float* st   = (float*)Wq;
  u16*   stTb = (u16*)(ws + SZ_X + 67108864L);
  u16* gated = qact;               // overlays qkv activations (dead after attention)
  if (ws_size < (size_t)(SZ_X + SZ_WQ + SZ_WG + SZ_WO + SZ_QA + SZ_AT)) return;

  cvt_kernel<<<1024, 256, 0, stream>>>(hidden, Xb, 33554432L);
  cvt_kernel<<<1024, 256, 0, stream>>>(qkv_w,  Wq, 50331648L);
  cvt_kernel<<<1024, 256, 0, stream>>>(gate_w, Wg, 16777216L);
  cvt_kernel<<<1024, 256, 0, stream>>>(out_w,  Wo, 16777216L);

  gemm_bt<0><<<64 * 96, 256, 0, stream>>>(Xb, Wq, (void*)qact, nullptr, 8192, 12288, 4096);

  attn_contrib<<<1024, 256, 0, stream>>>(qact, st);
  attn_scan<<<64, 256, 0, stream>>>(st, stTb);
  attn_mfma<<<1024, 512, 0, stream>>>(qact, stTb, attn);
  rmsnorm_ip<<<8192, 256, 0, stream>>>(attn, norm_w);

  gemm_bt<1><<<64 * 32, 256, 0, stream>>>(Xb, Wg, (void*)gated, attn, 8192, 4096, 4096);
  gemm_bt<2><<<64 * 32, 256, 0, stream>>>(gated, Wo, d_out, nullptr, 8192, 4096, 4096);
}

// Round 3
// 1903.344 us; speedup vs baseline: 2.5857x; 1.3169x over previous
//
#include <hip/hip_runtime.h>

typedef unsigned short u16;
typedef __attribute__((ext_vector_type(4))) float f32x4;
typedef __attribute__((ext_vector_type(8))) __bf16 bf16x8;

#define SEQ   4096
#define HID   4096
#define HID3  12288

__device__ __forceinline__ float bf2f(u16 u){
  union { unsigned int i; float f; } v; v.i = ((unsigned int)u) << 16; return v.f;
}
__device__ __forceinline__ u16 f2bf(float f){
  union { float f; unsigned int i; } v; v.f = f;
  unsigned int r = (v.i + 0x7FFFu + ((v.i >> 16) & 1u)) >> 16;
  return (u16)r;
}
__device__ __forceinline__ float slope_of(int h){
  const float factor = 1.0f - 1.0f/(31.0f + 1e-5f) + 1e-5f;
  return exp2f(-0.25f * (float)(h + 1)) * factor;
}
__device__ __forceinline__ bf16x8 ld_bf8(const u16* p){
  return __builtin_bit_cast(bf16x8, *(const uint4*)p);
}
__device__ __forceinline__ void gload_lds16(const u16* g, u16* l){
  __builtin_amdgcn_global_load_lds((const __attribute__((address_space(1))) void*)g,
                                   (__attribute__((address_space(3))) void*)l, 16, 0, 0);
}

// ---------------- fp32 -> bf16 convert (vectorized) ----------------
__global__ __launch_bounds__(256) void cvt_kernel(const float* __restrict__ in,
                                                  u16* __restrict__ out, long n){
  long i = ((long)blockIdx.x * 256 + threadIdx.x) * 4;
  long stride = (long)gridDim.x * 1024;
  for (; i < n; i += stride){
    float4 v = *(const float4*)(in + i);
    ushort4 o;
    o.x = f2bf(v.x); o.y = f2bf(v.y); o.z = f2bf(v.z); o.w = f2bf(v.w);
    *(ushort4*)(out + i) = o;
  }
}

// ============ 256x256 tile, BK=64, 5-slot-ring, counted-vmcnt bf16 GEMM ============
// C[M][N] = A[M][K] * B[N][K]^T.  512 threads = 8 waves (2 M x 4 N).
// Ring slot s (32KB): A-chunk [256 rows][32 k] swizzled (16KB) + B-chunk same (16KB).
// Tile kt uses slots (2kt)%5,(2kt+1)%5. Period p stages chunk (p+1,1) in phases 0-1
// and (p+2,0) in phases 2-3; boundary waits vmcnt(4) (the (p+2,0) loads stay in flight).
// Swizzle: row-pair dr=row>>1 holds 8x16B units; unit = ((row&1)*4 + k8) ^ (dr&7).
// global_load_lds writes linear; the global SOURCE is pre-permuted to match (rule 21).
template<int EPI>
__global__ __launch_bounds__(512) void gemm256(
    const u16* __restrict__ A, const u16* __restrict__ B, void* __restrict__ C,
    const u16* __restrict__ Aux, int M, int N, int K)
{
  __shared__ u16 ring[5][16384];
  const int t = threadIdx.x;
  const int w = t >> 6, l = t & 63, lr = l & 15, lk = l >> 4;
  const int mw = w >> 2, nw = w & 3;
  const int nbn = N >> 8;
  int nwg = gridDim.x;
  int bid = blockIdx.x;
  int bswz = (bid & 7) * (nwg >> 3) + (bid >> 3);
  int bm = bswz / nbn, bn = bswz % nbn;
  const u16* Abase = A + (long)(bm * 256) * K;
  const u16* Bbase = B + (long)(bn * 256) * K;
  const int NT = K >> 6;

  // staging decode: issue i covers LDS bytes [i*8192 + t*16, +16)
  int sr[2], sku[2];
#pragma unroll
  for (int i = 0; i < 2; ++i){
    int dr = i * 64 + (t >> 3);
    int ul = (t & 7) ^ (dr & 7);
    sr[i]  = 2 * dr + (ul >> 2);
    sku[i] = ul & 3;
  }
  // frag read offsets (u16 units within a 16KB chunk)
  int offA[8], offB[4];
#pragma unroll
  for (int fn = 0; fn < 8; ++fn){
    int row = mw * 128 + fn * 16 + lr;
    offA[fn] = (row >> 1) * 64 + (((((row & 1) << 2) + lk) ^ ((row >> 1) & 7)) << 3);
  }
#pragma unroll
  for (int fe = 0; fe < 4; ++fe){
    int row = nw * 64 + fe * 16 + lr;
    offB[fe] = (row >> 1) * 64 + (((((row & 1) << 2) + lk) ^ ((row >> 1) & 7)) << 3);
  }

  auto stageA = [&](int kt, int c, int slot, int i){
    gload_lds16(Abase + (long)sr[i] * K + kt * 64 + c * 32 + sku[i] * 8,
                &ring[slot][i * 4096 + w * 512]);
  };
  auto stageB = [&](int kt, int c, int slot, int i){
    gload_lds16(Bbase + (long)sr[i] * K + kt * 64 + c * 32 + sku[i] * 8,
                &ring[slot][8192 + i * 4096 + w * 512]);
  };

  f32x4 acc[8][4] = {};

  // prologue: (0,0)->slot0, (0,1)->slot1, (1,0)->slot2
  stageA(0,0,0,0); stageA(0,0,0,1); stageB(0,0,0,0); stageB(0,0,0,1);
  stageA(0,1,1,0); stageA(0,1,1,1); stageB(0,1,1,0); stageB(0,1,1,1);
  if (1 < NT){ stageA(1,0,2,0); stageA(1,0,2,1); stageB(1,0,2,0); stageB(1,0,2,1); }
  asm volatile("s_waitcnt vmcnt(4)" ::: "memory");
  __builtin_amdgcn_s_barrier();

  int sa = 0;
  for (int p = 0; p < NT; ++p){
    int sb = sa + 1; if (sb >= 5) sb -= 5;
    int sx = sa + 3; if (sx >= 5) sx -= 5;   // chunk (p+1,1)
    int sy = sa + 4; if (sy >= 5) sy -= 5;   // chunk (p+2,0)
    const u16* Aa = &ring[sa][0];
    const u16* Ab = &ring[sb][0];
    const u16* Ba = &ring[sa][8192];
    const u16* Bb = &ring[sb][8192];
    bf16x8 bh[4][2];
#pragma unroll
    for (int q = 0; q < 4; ++q){
      // ---- ds-reads for this phase ----
      bf16x8 af[2][2];
#pragma unroll
      for (int fnl = 0; fnl < 2; ++fnl){
        af[fnl][0] = ld_bf8(Aa + offA[q * 2 + fnl]);
        af[fnl][1] = ld_bf8(Ab + offA[q * 2 + fnl]);
      }
      if (q == 0){
#pragma unroll
        for (int fe = 0; fe < 4; ++fe){
          bh[fe][0] = ld_bf8(Ba + offB[fe]);
          bh[fe][1] = ld_bf8(Bb + offB[fe]);
        }
      }
      // ---- stage prefetch ----
      if (q == 0 && p + 1 < NT){ stageA(p+1, 1, sx, 0); stageA(p+1, 1, sx, 1); }
      if (q == 1 && p + 1 < NT){ stageB(p+1, 1, sx, 0); stageB(p+1, 1, sx, 1); }
      if (q == 2 && p + 2 < NT){ stageA(p+2, 0, sy, 0); stageA(p+2, 0, sy, 1); }
      if (q == 3 && p + 2 < NT){ stageB(p+2, 0, sy, 0); stageB(p+2, 0, sy, 1); }
      if (q == 0) asm volatile("s_waitcnt lgkmcnt(8)" ::: "memory");
      __builtin_amdgcn_s_barrier();
      asm volatile("s_waitcnt lgkmcnt(0)" ::: "memory");
      __builtin_amdgcn_sched_barrier(0);
      __builtin_amdgcn_s_setprio(1);
#pragma unroll
      for (int fnl = 0; fnl < 2; ++fnl)
#pragma unroll
        for (int fe = 0; fe < 4; ++fe){
          acc[q*2+fnl][fe] = __builtin_amdgcn_mfma_f32_16x16x32_bf16(af[fnl][0], bh[fe][0], acc[q*2+fnl][fe], 0, 0, 0);
          acc[q*2+fnl][fe] = __builtin_amdgcn_mfma_f32_16x16x32_bf16(af[fnl][1], bh[fe][1], acc[q*2+fnl][fe], 0, 0, 0);
        }
      __builtin_amdgcn_s_setprio(0);
      if (q == 3){
        if (p + 2 < NT) asm volatile("s_waitcnt vmcnt(4)" ::: "memory");
        else            asm volatile("s_waitcnt vmcnt(0)" ::: "memory");
      }
      __builtin_amdgcn_s_barrier();
    }
    sa += 2; if (sa >= 5) sa -= 5;
  }

  long crow = (long)bm * 256 + mw * 128 + lk * 4;
  long ccol = (long)bn * 256 + nw * 64 + lr;
#pragma unroll
  for (int fn = 0; fn < 8; ++fn)
#pragma unroll
    for (int fe = 0; fe < 4; ++fe)
#pragma unroll
      for (int reg = 0; reg < 4; ++reg){
        long row = crow + fn * 16 + reg;
        long col = ccol + fe * 16;
        float x = acc[fn][fe][reg];
        if (EPI == 0){
          ((u16*)C)[row * N + col] = f2bf(x / (1.0f + __expf(-x)));
        } else if (EPI == 1){
          float g = 1.0f / (1.0f + __expf(-x));
          ((u16*)C)[row * N + col] = f2bf(g * bf2f(Aux[row * N + col]));
        } else {
          ((float*)C)[row * N + col] = x;
        }
      }
}

// ---------------- attention phase 1: contribT[e][d] = sum_n v[n][e]*k[n][d]*kdec[n] ----
__global__ __launch_bounds__(256) void attn_contrib(
    const u16* __restrict__ qkv, float* __restrict__ ct)
{
  __shared__ u16 kb[256 * 128];
  __shared__ u16 vb[256 * 128];
  __shared__ float kdec[256];
  int wg = blockIdx.x;
  int bh = wg >> 4, blk = wg & 15;
  int b = bh >> 5, h = bh & 31;
  int t = threadIdx.x;
  float slope = slope_of(h);
  kdec[t] = __expf(-slope * (float)(255 - t));
  const u16* kg = qkv + ((long)(b * SEQ + blk * 256)) * HID3 + h * 384 + 128;
  const u16* vg = kg + 128;
#pragma unroll
  for (int i = 0; i < 16; ++i){
    int chunk = t + i * 256;
    int row = chunk >> 4, c8 = (chunk & 15) << 3;
    *(uint4*)&kb[row * 128 + c8] = *(const uint4*)&kg[(long)row * HID3 + c8];
    *(uint4*)&vb[row * 128 + c8] = *(const uint4*)&vg[(long)row * HID3 + c8];
  }
  __syncthreads();
  int e0 = (t >> 4) << 3, d0 = (t & 15) << 3;
  float acc[8][8];
#pragma unroll
  for (int i = 0; i < 8; ++i)
#pragma unroll
    for (int j = 0; j < 8; ++j) acc[i][j] = 0.f;
  for (int n = 0; n < 256; ++n){
    float kd = kdec[n];
    uint4 vv = *(const uint4*)&vb[n * 128 + e0];
    uint4 kk = *(const uint4*)&kb[n * 128 + d0];
    const u16* vs = (const u16*)&vv;
    const u16* ks = (const u16*)&kk;
    float ve[8], kf[8];
#pragma unroll
    for (int x = 0; x < 8; ++x){ ve[x] = bf2f(vs[x]); kf[x] = bf2f(ks[x]) * kd; }
#pragma unroll
    for (int i = 0; i < 8; ++i)
#pragma unroll
      for (int j = 0; j < 8; ++j) acc[i][j] += ve[i] * kf[j];
  }
  float* out = ct + (long)wg * 16384;
#pragma unroll
  for (int i = 0; i < 8; ++i){
    *(float4*)&out[(e0 + i) * 128 + d0]     = make_float4(acc[i][0], acc[i][1], acc[i][2], acc[i][3]);
    *(float4*)&out[(e0 + i) * 128 + d0 + 4] = make_float4(acc[i][4], acc[i][5], acc[i][6], acc[i][7]);
  }
}

// ---------------- attention phase 2: decayed prefix scan; emits bf16 pre-state ----
__global__ __launch_bounds__(256) void attn_scan(const float* __restrict__ ct,
                                                 u16* __restrict__ stTb)
{
  int bh = blockIdx.x, t = threadIdx.x;
  float bdec = __expf(-slope_of(bh & 31) * 256.0f);
  float cur[64];
#pragma unroll
  for (int i = 0; i < 64; ++i) cur[i] = 0.f;
  const float* base = ct + (long)bh * 16 * 16384;
  u16* ob = stTb + (long)bh * 16 * 16384;
  for (int blkI = 0; blkI < 16; ++blkI){
    const float* p = base + (long)blkI * 16384;
    u16* o = ob + (long)blkI * 16384;
#pragma unroll
    for (int i = 0; i < 64; ++i){
      o[t + i * 256] = f2bf(cur[i]);
      cur[i] = cur[i] * bdec + p[t + i * 256];
    }
  }
}

// ---------------- attention phase 3 (MFMA): intra (causal decay) + inter ----
__global__ __launch_bounds__(512) void attn_mfma(
    const u16* __restrict__ qkv, const u16* __restrict__ stTb, u16* __restrict__ attn)
{
  __shared__ u16 Ks[256 * 130];
  __shared__ u16 VTs[128 * 258];
  __shared__ u16 Ps[4][64 * 34];
  int wg = blockIdx.x;
  int bh = wg >> 4, blk = wg & 15;
  int b = bh >> 5, h = bh & 31;
  int t = threadIdx.x;
  int w = t >> 6, l = t & 63, lr = l & 15, lk = l >> 4;
  int r = w >> 1, c = w & 1;
  float slope = slope_of(h);
  const u16* qg = qkv + ((long)(b * SEQ + blk * 256)) * HID3 + h * 384;
  const u16* kg = qg + 128;
  const u16* vg = qg + 256;

#pragma unroll
  for (int i = 0; i < 8; ++i){
    int chunk = t + i * 512;
    int row = chunk >> 4, c8 = (chunk & 15) << 3;
    *(uint4*)&Ks[row * 130 + c8] = *(const uint4*)&kg[(long)row * HID3 + c8];
    uint4 vv = *(const uint4*)&vg[(long)row * HID3 + c8];
    const u16* vs = (const u16*)&vv;
#pragma unroll
    for (int x = 0; x < 8; ++x) VTs[(c8 + x) * 258 + row] = vs[x];
  }
  bf16x8 qa[4][4];
#pragma unroll
  for (int fn = 0; fn < 4; ++fn)
#pragma unroll
    for (int kc = 0; kc < 4; ++kc)
      qa[fn][kc] = ld_bf8(&qg[(long)(r * 64 + fn * 16 + lr) * HID3 + kc * 32 + lk * 8]);
  f32x4 acc[4][4] = {};
  __syncthreads();

  int mtmax = 2 * r + 1;
  for (int mt = 0; mt < 8; ++mt){
    if (mt <= mtmax){
      f32x4 S[4] = {};
      int mrow = mt * 32 + c * 16 + lr;
      bf16x8 kb[4];
#pragma unroll
      for (int kc = 0; kc < 4; ++kc)
        kb[kc] = ld_bf8(&Ks[mrow * 130 + kc * 32 + lk * 8]);
#pragma unroll
      for (int fn = 0; fn < 4; ++fn)
#pragma unroll
        for (int kc = 0; kc < 4; ++kc)
          S[fn] = __builtin_amdgcn_mfma_f32_16x16x32_bf16(qa[fn][kc], kb[kc], S[fn], 0, 0, 0);
      int m = mt * 32 + c * 16 + lr;
#pragma unroll
      for (int fn = 0; fn < 4; ++fn)
#pragma unroll
        for (int reg = 0; reg < 4; ++reg){
          int n = r * 64 + fn * 16 + lk * 4 + reg;
          float dv = (n >= m) ? __expf(-slope * (float)(n - m)) : 0.f;
          Ps[r][(fn * 16 + lk * 4 + reg) * 34 + c * 16 + lr] = f2bf(S[fn][reg] * dv);
        }
    }
    __syncthreads();
    if (mt <= mtmax){
      bf16x8 pa[4], vb[4];
#pragma unroll
      for (int fn = 0; fn < 4; ++fn)
        pa[fn] = ld_bf8(&Ps[r][(fn * 16 + lr) * 34 + lk * 8]);
#pragma unroll
      for (int fe = 0; fe < 4; ++fe)
        vb[fe] = ld_bf8(&VTs[(c * 64 + fe * 16 + lr) * 258 + mt * 32 + lk * 8]);
#pragma unroll
      for (int fn = 0; fn < 4; ++fn)
#pragma unroll
        for (int fe = 0; fe < 4; ++fe)
          acc[fn][fe] = __builtin_amdgcn_mfma_f32_16x16x32_bf16(pa[fn], vb[fe], acc[fn][fe], 0, 0, 0);
    }
    __syncthreads();
  }

#pragma unroll
  for (int fn = 0; fn < 4; ++fn){
    int n = r * 64 + fn * 16 + lr;
    float qd = __expf(-slope * (float)(n + 1));
#pragma unroll
    for (int kc = 0; kc < 4; ++kc){
      union { bf16x8 v; u16 u[8]; } uu; uu.v = qa[fn][kc];
#pragma unroll
      for (int x = 0; x < 8; ++x) uu.u[x] = f2bf(bf2f(uu.u[x]) * qd);
      qa[fn][kc] = uu.v;
    }
  }
  const u16* sg = stTb + (long)(bh * 16 + blk) * 16384;
#pragma unroll
  for (int kc = 0; kc < 4; ++kc){
    bf16x8 sb2[4];
#pragma unroll
    for (int fe = 0; fe < 4; ++fe)
      sb2[fe] = ld_bf8(&sg[(c * 64 + fe * 16 + lr) * 128 + kc * 32 + lk * 8]);
#pragma unroll
    for (int fn = 0; fn < 4; ++fn)
#pragma unroll
      for (int fe = 0; fe < 4; ++fe)
        acc[fn][fe] = __builtin_amdgcn_mfma_f32_16x16x32_bf16(qa[fn][kc], sb2[fe], acc[fn][fe], 0, 0, 0);
  }

  u16* arow = attn + ((long)(b * SEQ + blk * 256)) * HID + h * 128;
#pragma unroll
  for (int fn = 0; fn < 4; ++fn)
#pragma unroll
    for (int fe = 0; fe < 4; ++fe)
#pragma unroll
      for (int reg = 0; reg < 4; ++reg){
        int n = r * 64 + fn * 16 + lk * 4 + reg;
        int col = c * 64 + fe * 16 + lr;
        arow[(long)n * HID + col] = f2bf(acc[fn][fe][reg]);
      }
}

// ---------------- RMSNorm in-place on attn rows ----------------
__global__ __launch_bounds__(256) void rmsnorm_ip(u16* __restrict__ attn,
                                                  const float* __restrict__ nw)
{
  __shared__ float wsum[4];
  int row = blockIdx.x, t = threadIdx.x;
  u16* p = attn + (long)row * HID;
  uint4 v0 = *(const uint4*)&p[t * 8];
  uint4 v1 = *(const uint4*)&p[t * 8 + 2048];
  const u16* a0 = (const u16*)&v0;
  const u16* a1 = (const u16*)&v1;
  float f0[8], f1[8];
  float ss = 0.f;
#pragma unroll
  for (int x = 0; x < 8; ++x){
    f0[x] = bf2f(a0[x]); f1[x] = bf2f(a1[x]);
    ss += f0[x] * f0[x] + f1[x] * f1[x];
  }
#pragma unroll
  for (int off = 32; off > 0; off >>= 1) ss += __shfl_down(ss, off);
  if ((t & 63) == 0) wsum[t >> 6] = ss;
  __syncthreads();
  float rs = rsqrtf((wsum[0] + wsum[1] + wsum[2] + wsum[3]) * (1.0f / 4096.0f) + 1e-5f);
  alignas(16) u16 o0[8], o1[8];
#pragma unroll
  for (int x = 0; x < 8; ++x){
    o0[x] = f2bf(f0[x] * rs * nw[t * 8 + x]);
    o1[x] = f2bf(f1[x] * rs * nw[t * 8 + 2048 + x]);
  }
  *(uint4*)&p[t * 8]        = *(const uint4*)&o0[0];
  *(uint4*)&p[t * 8 + 2048] = *(const uint4*)&o1[0];
}

// ---------------- launch ----------------
extern "C" void kernel_launch(void* const* d_in, const int* in_sizes, int n_in,
                              void* d_out, int out_size, void* d_ws, size_t ws_size,
                              hipStream_t stream)
{
  const float* hidden = (const float*)d_in[0];
  const float* qkv_w  = (const float*)d_in[1];
  const float* out_w  = (const float*)d_in[2];
  const float* gate_w = (const float*)d_in[3];
  const float* norm_w = (const float*)d_in[4];
  char* ws = (char*)d_ws;
  const long SZ_X  = 67108864L;    // 8192*4096 bf16
  const long SZ_WQ = 100663296L;   // 12288*4096 bf16
  const long SZ_WG = 33554432L;
  const long SZ_WO = 33554432L;
  const long SZ_QA = 201326592L;   // 8192*12288 bf16
  const long SZ_AT = 67108864L;    // 8192*4096 bf16
  u16* Xb   = (u16*)(ws);
  u16* Wq   = (u16*)(ws + SZ_X);
  u16* Wg   = (u16*)(ws + SZ_X + SZ_WQ);
  u16* Wo   = (u16*)(ws + SZ_X + SZ_WQ + SZ_WG);
  u16* qact = (u16*)(ws + SZ_X + SZ_WQ + SZ_WG + SZ_WO);
  u16* attn = (u16*)(ws + SZ_X + SZ_WQ + SZ_WG + SZ_WO + SZ_QA);
  float* st   = (float*)Wq;        // overlays Wq (dead after gemm<0>)
  u16*   stTb = (u16*)(ws + SZ_X + 67108864L);
  u16* gated = qact;               // overlays qkv activations (dead after attention)
  if (ws_size < (size_t)(SZ_X + SZ_WQ + SZ_WG + SZ_WO + SZ_QA + SZ_AT)) return;

  cvt_kernel<<<1024, 256, 0, stream>>>(hidden, Xb, 33554432L);
  cvt_kernel<<<1024, 256, 0, stream>>>(qkv_w,  Wq, 50331648L);
  cvt_kernel<<<1024, 256, 0, stream>>>(gate_w, Wg, 16777216L);
  cvt_kernel<<<1024, 256, 0, stream>>>(out_w,  Wo, 16777216L);

  gemm256<0><<<32 * 48, 512, 0, stream>>>(Xb, Wq, (void*)qact, nullptr, 8192, 12288, 4096);

  attn_contrib<<<1024, 256, 0, stream>>>(qact, st);
  attn_scan<<<64, 256, 0, stream>>>(st, stTb);
  attn_mfma<<<1024, 512, 0, stream>>>(qact, stTb, attn);
  rmsnorm_ip<<<8192, 256, 0, stream>>>(attn, norm_w);

  gemm256<1><<<32 * 16, 512, 0, stream>>>(Xb, Wg, (void*)gated, attn, 8192, 4096, 4096);
  gemm256<2><<<32 * 16, 512, 0, stream>>>(gated, Wo, d_out, nullptr, 8192, 4096, 4096);
}

// Round 4
// 1698.857 us; speedup vs baseline: 2.8970x; 1.1204x over previous
//
#include <hip/hip_runtime.h>

typedef unsigned short u16;
typedef __attribute__((ext_vector_type(4))) float f32x4;
typedef __attribute__((ext_vector_type(8))) __bf16 bf16x8;

#define SEQ   4096
#define HID   4096
#define HID3  12288

__device__ __forceinline__ float bf2f(u16 u){
  union { unsigned int i; float f; } v; v.i = ((unsigned int)u) << 16; return v.f;
}
__device__ __forceinline__ u16 f2bf(float f){
  union { float f; unsigned int i; } v; v.f = f;
  unsigned int r = (v.i + 0x7FFFu + ((v.i >> 16) & 1u)) >> 16;
  return (u16)r;
}
__device__ __forceinline__ float slope_of(int h){
  const float factor = 1.0f - 1.0f/(31.0f + 1e-5f) + 1e-5f;
  return exp2f(-0.25f * (float)(h + 1)) * factor;
}
__device__ __forceinline__ bf16x8 ld_bf8(const u16* p){
  return __builtin_bit_cast(bf16x8, *(const uint4*)p);
}
__device__ __forceinline__ void gload_lds16(const u16* g, u16* l){
  __builtin_amdgcn_global_load_lds((const __attribute__((address_space(1))) void*)g,
                                   (__attribute__((address_space(3))) void*)l, 16, 0, 0);
}

// ---------------- fp32 -> bf16 convert (vectorized) ----------------
__global__ __launch_bounds__(256) void cvt_kernel(const float* __restrict__ in,
                                                  u16* __restrict__ out, long n){
  long i = ((long)blockIdx.x * 256 + threadIdx.x) * 4;
  long stride = (long)gridDim.x * 1024;
  for (; i < n; i += stride){
    float4 v = *(const float4*)(in + i);
    ushort4 o;
    o.x = f2bf(v.x); o.y = f2bf(v.y); o.z = f2bf(v.z); o.w = f2bf(v.w);
    *(ushort4*)(out + i) = o;
  }
}

// ============ 256x256 tile, BK=64, 5-slot-ring, 1-barrier/period bf16 GEMM ============
// C[M][N] = A[M][K] * B[N][K]^T.  512 threads = 8 waves (2 M x 4 N).
// Ring slot s (32KB): A-chunk [256 rows][32 k] swizzled (16KB) + B-chunk same (16KB).
// Period p consumes slots sa=(2p)%5, sb=(2p+1)%5; stages (p+1,1)->sx=(2p+3)%5 and
// (p+2,0)->sy=(2p+4)%5. Boundary: lgkmcnt(0) (reads drained) + vmcnt(4) ((p+1,*)
// writes drained, (p+2,0) stays in flight) + ONE s_barrier. No intra-period barriers:
// staged slots are disjoint from consumed slots, so only the boundary is a hazard.
// Counted lgkm waits pipeline frag ds_reads one MFMA-quad ahead of use.
template<int EPI>
__global__ __launch_bounds__(512) void gemm256(
    const u16* __restrict__ A, const u16* __restrict__ B, void* __restrict__ C,
    const u16* __restrict__ Aux, int M, int N, int K)
{
  __shared__ u16 ring[5][16384];
  const int t = threadIdx.x;
  const int w = t >> 6, l = t & 63, lr = l & 15, lk = l >> 4;
  const int mw = w >> 2, nw = w & 3;
  const int nbn = N >> 8;
  int nwg = gridDim.x;
  int bid = blockIdx.x;
  int bswz = (bid & 7) * (nwg >> 3) + (bid >> 3);
  int bm = bswz / nbn, bn = bswz % nbn;
  const u16* Abase = A + (long)(bm * 256) * K;
  const u16* Bbase = B + (long)(bn * 256) * K;
  const int NT = K >> 6;

  // staging decode: issue i covers LDS bytes [i*8192 + t*16, +16)
  int sr[2], sku[2];
#pragma unroll
  for (int i = 0; i < 2; ++i){
    int dr = i * 64 + (t >> 3);
    int ul = (t & 7) ^ (dr & 7);
    sr[i]  = 2 * dr + (ul >> 2);
    sku[i] = ul & 3;
  }
  // frag read offsets (u16 units within a 16KB chunk)
  int offA[8], offB[4];
#pragma unroll
  for (int fn = 0; fn < 8; ++fn){
    int row = mw * 128 + fn * 16 + lr;
    offA[fn] = (row >> 1) * 64 + (((((row & 1) << 2) + lk) ^ ((row >> 1) & 7)) << 3);
  }
#pragma unroll
  for (int fe = 0; fe < 4; ++fe){
    int row = nw * 64 + fe * 16 + lr;
    offB[fe] = (row >> 1) * 64 + (((((row & 1) << 2) + lk) ^ ((row >> 1) & 7)) << 3);
  }

  auto stageA = [&](int kt, int c, int slot, int i){
    gload_lds16(Abase + (long)sr[i] * K + kt * 64 + c * 32 + sku[i] * 8,
                &ring[slot][i * 4096 + w * 512]);
  };
  auto stageB = [&](int kt, int c, int slot, int i){
    gload_lds16(Bbase + (long)sr[i] * K + kt * 64 + c * 32 + sku[i] * 8,
                &ring[slot][8192 + i * 4096 + w * 512]);
  };

  f32x4 acc[8][4] = {};

  // prologue: (0,0)->slot0, (0,1)->slot1, (1,0)->slot2
  stageA(0,0,0,0); stageA(0,0,0,1); stageB(0,0,0,0); stageB(0,0,0,1);
  stageA(0,1,1,0); stageA(0,1,1,1); stageB(0,1,1,0); stageB(0,1,1,1);
  if (1 < NT){ stageA(1,0,2,0); stageA(1,0,2,1); stageB(1,0,2,0); stageB(1,0,2,1); }
  asm volatile("s_waitcnt vmcnt(4)" ::: "memory");
  __builtin_amdgcn_s_barrier();

  int sa = 0;
  for (int p = 0; p < NT; ++p){
    int sb = sa + 1; if (sb >= 5) sb -= 5;
    int sx = sa + 3; if (sx >= 5) sx -= 5;   // chunk (p+1,1)
    int sy = sa + 4; if (sy >= 5) sy -= 5;   // chunk (p+2,0)
    const u16* Aa = &ring[sa][0];
    const u16* Ab = &ring[sb][0];
    const u16* Ba = &ring[sa][8192];
    const u16* Bb = &ring[sb][8192];
    bf16x8 bh[4][2], af[4][2][2];
#pragma unroll
    for (int q = 0; q < 4; ++q){
      // ---- issue this phase's ds_reads / staging ----
      if (q == 0){
#pragma unroll
        for (int fe = 0; fe < 4; ++fe){
          bh[fe][0] = ld_bf8(Ba + offB[fe]);
          bh[fe][1] = ld_bf8(Bb + offB[fe]);
        }
#pragma unroll
        for (int fnl = 0; fnl < 2; ++fnl){
          af[0][fnl][0] = ld_bf8(Aa + offA[fnl]);
          af[0][fnl][1] = ld_bf8(Ab + offA[fnl]);
        }
#pragma unroll
        for (int fnl = 0; fnl < 2; ++fnl){
          af[1][fnl][0] = ld_bf8(Aa + offA[2 + fnl]);
          af[1][fnl][1] = ld_bf8(Ab + offA[2 + fnl]);
        }
        if (p + 1 < NT){ stageA(p+1, 1, sx, 0); stageA(p+1, 1, sx, 1); }
      } else if (q == 1){
#pragma unroll
        for (int fnl = 0; fnl < 2; ++fnl){
          af[2][fnl][0] = ld_bf8(Aa + offA[4 + fnl]);
          af[2][fnl][1] = ld_bf8(Ab + offA[4 + fnl]);
        }
        if (p + 1 < NT){ stageB(p+1, 1, sx, 0); stageB(p+1, 1, sx, 1); }
      } else if (q == 2){
#pragma unroll
        for (int fnl = 0; fnl < 2; ++fnl){
          af[3][fnl][0] = ld_bf8(Aa + offA[6 + fnl]);
          af[3][fnl][1] = ld_bf8(Ab + offA[6 + fnl]);
        }
        if (p + 2 < NT){ stageA(p+2, 0, sy, 0); stageA(p+2, 0, sy, 1); }
      } else {
        if (p + 2 < NT){ stageB(p+2, 0, sy, 0); stageB(p+2, 0, sy, 1); }
      }
      // ---- counted wait: this quad's frags ready, next quad's in flight ----
      if (q < 3) asm volatile("s_waitcnt lgkmcnt(4)" ::: "memory");
      else       asm volatile("s_waitcnt lgkmcnt(0)" ::: "memory");
      __builtin_amdgcn_sched_barrier(0);
      __builtin_amdgcn_s_setprio(1);
#pragma unroll
      for (int fnl = 0; fnl < 2; ++fnl)
#pragma unroll
        for (int fe = 0; fe < 4; ++fe){
          acc[q*2+fnl][fe] = __builtin_amdgcn_mfma_f32_16x16x32_bf16(af[q][fnl][0], bh[fe][0], acc[q*2+fnl][fe], 0, 0, 0);
          acc[q*2+fnl][fe] = __builtin_amdgcn_mfma_f32_16x16x32_bf16(af[q][fnl][1], bh[fe][1], acc[q*2+fnl][fe], 0, 0, 0);
        }
      __builtin_amdgcn_s_setprio(0);
    }
    // ---- single boundary sync per period ----
    if (p + 2 < NT) asm volatile("s_waitcnt vmcnt(4)" ::: "memory");
    else            asm volatile("s_waitcnt vmcnt(0)" ::: "memory");
    __builtin_amdgcn_s_barrier();
    sa += 2; if (sa >= 5) sa -= 5;
  }

  long crow = (long)bm * 256 + mw * 128 + lk * 4;
  long ccol = (long)bn * 256 + nw * 64 + lr;
#pragma unroll
  for (int fn = 0; fn < 8; ++fn)
#pragma unroll
    for (int fe = 0; fe < 4; ++fe)
#pragma unroll
      for (int reg = 0; reg < 4; ++reg){
        long row = crow + fn * 16 + reg;
        long col = ccol + fe * 16;
        float x = acc[fn][fe][reg];
        if (EPI == 0){
          ((u16*)C)[row * N + col] = f2bf(x / (1.0f + __expf(-x)));
        } else if (EPI == 1){
          float g = 1.0f / (1.0f + __expf(-x));
          ((u16*)C)[row * N + col] = f2bf(g * bf2f(Aux[row * N + col]));
        } else {
          ((float*)C)[row * N + col] = x;
        }
      }
}

// ---------------- attention phase 1: contribT[e][d] = sum_n v[n][e]*k[n][d]*kdec[n] ----
__global__ __launch_bounds__(256) void attn_contrib(
    const u16* __restrict__ qkv, float* __restrict__ ct)
{
  __shared__ u16 kb[256 * 128];
  __shared__ u16 vb[256 * 128];
  __shared__ float kdec[256];
  int wg = blockIdx.x;
  int bh = wg >> 4, blk = wg & 15;
  int b = bh >> 5, h = bh & 31;
  int t = threadIdx.x;
  float slope = slope_of(h);
  kdec[t] = __expf(-slope * (float)(255 - t));
  const u16* kg = qkv + ((long)(b * SEQ + blk * 256)) * HID3 + h * 384 + 128;
  const u16* vg = kg + 128;
#pragma unroll
  for (int i = 0; i < 16; ++i){
    int chunk = t + i * 256;
    int row = chunk >> 4, c8 = (chunk & 15) << 3;
    *(uint4*)&kb[row * 128 + c8] = *(const uint4*)&kg[(long)row * HID3 + c8];
    *(uint4*)&vb[row * 128 + c8] = *(const uint4*)&vg[(long)row * HID3 + c8];
  }
  __syncthreads();
  int e0 = (t >> 4) << 3, d0 = (t & 15) << 3;
  float acc[8][8];
#pragma unroll
  for (int i = 0; i < 8; ++i)
#pragma unroll
    for (int j = 0; j < 8; ++j) acc[i][j] = 0.f;
  for (int n = 0; n < 256; ++n){
    float kd = kdec[n];
    uint4 vv = *(const uint4*)&vb[n * 128 + e0];
    uint4 kk = *(const uint4*)&kb[n * 128 + d0];
    const u16* vs = (const u16*)&vv;
    const u16* ks = (const u16*)&kk;
    float ve[8], kf[8];
#pragma unroll
    for (int x = 0; x < 8; ++x){ ve[x] = bf2f(vs[x]); kf[x] = bf2f(ks[x]) * kd; }
#pragma unroll
    for (int i = 0; i < 8; ++i)
#pragma unroll
      for (int j = 0; j < 8; ++j) acc[i][j] += ve[i] * kf[j];
  }
  float* out = ct + (long)wg * 16384;
#pragma unroll
  for (int i = 0; i < 8; ++i){
    *(float4*)&out[(e0 + i) * 128 + d0]     = make_float4(acc[i][0], acc[i][1], acc[i][2], acc[i][3]);
    *(float4*)&out[(e0 + i) * 128 + d0 + 4] = make_float4(acc[i][4], acc[i][5], acc[i][6], acc[i][7]);
  }
}

// ---------------- attention phase 2: decayed prefix scan (d-sliced, 256 blocks) ----
__global__ __launch_bounds__(256) void attn_scan(const float* __restrict__ ct,
                                                 u16* __restrict__ stTb)
{
  int g = blockIdx.x;
  int bh = g >> 2, sl = g & 3;
  int t = threadIdx.x;
  float bdec = __expf(-slope_of(bh & 31) * 256.0f);
  float cur[16];
#pragma unroll
  for (int i = 0; i < 16; ++i) cur[i] = 0.f;
  const float* base = ct + (long)bh * 16 * 16384 + sl * 4096;
  u16* ob = stTb + (long)bh * 16 * 16384 + sl * 4096;
  for (int blkI = 0; blkI < 16; ++blkI){
    const float* p = base + (long)blkI * 16384;
    u16* o = ob + (long)blkI * 16384;
#pragma unroll
    for (int i = 0; i < 16; ++i){
      o[t + i * 256] = f2bf(cur[i]);
      cur[i] = cur[i] * bdec + p[t + i * 256];
    }
  }
}

// ---------------- attention phase 3 (MFMA): intra (causal decay) + inter ----
__global__ __launch_bounds__(512) void attn_mfma(
    const u16* __restrict__ qkv, const u16* __restrict__ stTb, u16* __restrict__ attn)
{
  __shared__ u16 Ks[256 * 130];
  __shared__ u16 VTs[128 * 258];
  __shared__ u16 Ps[4][64 * 34];
  int wg = blockIdx.x;
  int bh = wg >> 4, blk = wg & 15;
  int b = bh >> 5, h = bh & 31;
  int t = threadIdx.x;
  int w = t >> 6, l = t & 63, lr = l & 15, lk = l >> 4;
  int r = w >> 1, c = w & 1;
  float slope = slope_of(h);
  const u16* qg = qkv + ((long)(b * SEQ + blk * 256)) * HID3 + h * 384;
  const u16* kg = qg + 128;
  const u16* vg = qg + 256;

#pragma unroll
  for (int i = 0; i < 8; ++i){
    int chunk = t + i * 512;
    int row = chunk >> 4, c8 = (chunk & 15) << 3;
    *(uint4*)&Ks[row * 130 + c8] = *(const uint4*)&kg[(long)row * HID3 + c8];
    uint4 vv = *(const uint4*)&vg[(long)row * HID3 + c8];
    const u16* vs = (const u16*)&vv;
#pragma unroll
    for (int x = 0; x < 8; ++x) VTs[(c8 + x) * 258 + row] = vs[x];
  }
  bf16x8 qa[4][4];
#pragma unroll
  for (int fn = 0; fn < 4; ++fn)
#pragma unroll
    for (int kc = 0; kc < 4; ++kc)
      qa[fn][kc] = ld_bf8(&qg[(long)(r * 64 + fn * 16 + lr) * HID3 + kc * 32 + lk * 8]);
  f32x4 acc[4][4] = {};
  __syncthreads();

  int mtmax = 2 * r + 1;
  for (int mt = 0; mt < 8; ++mt){
    if (mt <= mtmax){
      f32x4 S[4] = {};
      int mrow = mt * 32 + c * 16 + lr;
      bf16x8 kb[4];
#pragma unroll
      for (int kc = 0; kc < 4; ++kc)
        kb[kc] = ld_bf8(&Ks[mrow * 130 + kc * 32 + lk * 8]);
#pragma unroll
      for (int fn = 0; fn < 4; ++fn)
#pragma unroll
        for (int kc = 0; kc < 4; ++kc)
          S[fn] = __builtin_amdgcn_mfma_f32_16x16x32_bf16(qa[fn][kc], kb[kc], S[fn], 0, 0, 0);
      int m = mt * 32 + c * 16 + lr;
#pragma unroll
      for (int fn = 0; fn < 4; ++fn)
#pragma unroll
        for (int reg = 0; reg < 4; ++reg){
          int n = r * 64 + fn * 16 + lk * 4 + reg;
          float dv = (n >= m) ? __expf(-slope * (float)(n - m)) : 0.f;
          Ps[r][(fn * 16 + lk * 4 + reg) * 34 + c * 16 + lr] = f2bf(S[fn][reg] * dv);
        }
    }
    __syncthreads();
    if (mt <= mtmax){
      bf16x8 pa[4], vb[4];
#pragma unroll
      for (int fn = 0; fn < 4; ++fn)
        pa[fn] = ld_bf8(&Ps[r][(fn * 16 + lr) * 34 + lk * 8]);
#pragma unroll
      for (int fe = 0; fe < 4; ++fe)
        vb[fe] = ld_bf8(&VTs[(c * 64 + fe * 16 + lr) * 258 + mt * 32 + lk * 8]);
#pragma unroll
      for (int fn = 0; fn < 4; ++fn)
#pragma unroll
        for (int fe = 0; fe < 4; ++fe)
          acc[fn][fe] = __builtin_amdgcn_mfma_f32_16x16x32_bf16(pa[fn], vb[fe], acc[fn][fe], 0, 0, 0);
    }
    __syncthreads();
  }

#pragma unroll
  for (int fn = 0; fn < 4; ++fn){
    int n = r * 64 + fn * 16 + lr;
    float qd = __expf(-slope * (float)(n + 1));
#pragma unroll
    for (int kc = 0; kc < 4; ++kc){
      union { bf16x8 v; u16 u[8]; } uu; uu.v = qa[fn][kc];
#pragma unroll
      for (int x = 0; x < 8; ++x) uu.u[x] = f2bf(bf2f(uu.u[x]) * qd);
      qa[fn][kc] = uu.v;
    }
  }
  const u16* sg = stTb + (long)(bh * 16 + blk) * 16384;
#pragma unroll
  for (int kc = 0; kc < 4; ++kc){
    bf16x8 sb2[4];
#pragma unroll
    for (int fe = 0; fe < 4; ++fe)
      sb2[fe] = ld_bf8(&sg[(c * 64 + fe * 16 + lr) * 128 + kc * 32 + lk * 8]);
#pragma unroll
    for (int fn = 0; fn < 4; ++fn)
#pragma unroll
      for (int fe = 0; fe < 4; ++fe)
        acc[fn][fe] = __builtin_amdgcn_mfma_f32_16x16x32_bf16(qa[fn][kc], sb2[fe], acc[fn][fe], 0, 0, 0);
  }

  u16* arow = attn + ((long)(b * SEQ + blk * 256)) * HID + h * 128;
#pragma unroll
  for (int fn = 0; fn < 4; ++fn)
#pragma unroll
    for (int fe = 0; fe < 4; ++fe)
#pragma unroll
      for (int reg = 0; reg < 4; ++reg){
        int n = r * 64 + fn * 16 + lk * 4 + reg;
        int col = c * 64 + fe * 16 + lr;
        arow[(long)n * HID + col] = f2bf(acc[fn][fe][reg]);
      }
}

// ---------------- RMSNorm in-place on attn rows ----------------
__global__ __launch_bounds__(256) void rmsnorm_ip(u16* __restrict__ attn,
                                                  const float* __restrict__ nw)
{
  __shared__ float wsum[4];
  int row = blockIdx.x, t = threadIdx.x;
  u16* p = attn + (long)row * HID;
  uint4 v0 = *(const uint4*)&p[t * 8];
  uint4 v1 = *(const uint4*)&p[t * 8 + 2048];
  const u16* a0 = (const u16*)&v0;
  const u16* a1 = (const u16*)&v1;
  float f0[8], f1[8];
  float ss = 0.f;
#pragma unroll
  for (int x = 0; x < 8; ++x){
    f0[x] = bf2f(a0[x]); f1[x] = bf2f(a1[x]);
    ss += f0[x] * f0[x] + f1[x] * f1[x];
  }
#pragma unroll
  for (int off = 32; off > 0; off >>= 1) ss += __shfl_down(ss, off);
  if ((t & 63) == 0) wsum[t >> 6] = ss;
  __syncthreads();
  float rs = rsqrtf((wsum[0] + wsum[1] + wsum[2] + wsum[3]) * (1.0f / 4096.0f) + 1e-5f);
  alignas(16) u16 o0[8], o1[8];
#pragma unroll
  for (int x = 0; x < 8; ++x){
    o0[x] = f2bf(f0[x] * rs * nw[t * 8 + x]);
    o1[x] = f2bf(f1[x] * rs * nw[t * 8 + 2048 + x]);
  }
  *(uint4*)&p[t * 8]        = *(const uint4*)&o0[0];
  *(uint4*)&p[t * 8 + 2048] = *(const uint4*)&o1[0];
}

// ---------------- launch ----------------
extern "C" void kernel_launch(void* const* d_in, const int* in_sizes, int n_in,
                              void* d_out, int out_size, void* d_ws, size_t ws_size,
                              hipStream_t stream)
{
  const float* hidden = (const float*)d_in[0];
  const float* qkv_w  = (const float*)d_in[1];
  const float* out_w  = (const float*)d_in[2];
  const float* gate_w = (const float*)d_in[3];
  const float* norm_w = (const float*)d_in[4];
  char* ws = (char*)d_ws;
  const long SZ_X  = 67108864L;    // 8192*4096 bf16
  const long SZ_WQ = 100663296L;   // 12288*4096 bf16
  const long SZ_WG = 33554432L;
  const long SZ_WO = 33554432L;
  const long SZ_QA = 201326592L;   // 8192*12288 bf16
  const long SZ_AT = 67108864L;    // 8192*4096 bf16
  u16* Xb   = (u16*)(ws);
  u16* Wq   = (u16*)(ws + SZ_X);
  u16* Wg   = (u16*)(ws + SZ_X + SZ_WQ);
  u16* Wo   = (u16*)(ws + SZ_X + SZ_WQ + SZ_WG);
  u16* qact = (u16*)(ws + SZ_X + SZ_WQ + SZ_WG + SZ_WO);
  u16* attn = (u16*)(ws + SZ_X + SZ_WQ + SZ_WG + SZ_WO + SZ_QA);
  float* st   = (float*)Wq;        // overlays Wq (dead after gemm<0>)
  u16*   stTb = (u16*)(ws + SZ_X + 67108864L);
  u16* gated = qact;               // overlays qkv activations (dead after attention)
  if (ws_size < (size_t)(SZ_X + SZ_WQ + SZ_WG + SZ_WO + SZ_QA + SZ_AT)) return;

  cvt_kernel<<<1024, 256, 0, stream>>>(hidden, Xb, 33554432L);
  cvt_kernel<<<1024, 256, 0, stream>>>(qkv_w,  Wq, 50331648L);
  cvt_kernel<<<1024, 256, 0, stream>>>(gate_w, Wg, 16777216L);
  cvt_kernel<<<1024, 256, 0, stream>>>(out_w,  Wo, 16777216L);

  gemm256<0><<<32 * 48, 512, 0, stream>>>(Xb, Wq, (void*)qact, nullptr, 8192, 12288, 4096);

  attn_contrib<<<1024, 256, 0, stream>>>(qact, st);
  attn_scan<<<256, 256, 0, stream>>>(st, stTb);
  attn_mfma<<<1024, 512, 0, stream>>>(qact, stTb, attn);
  rmsnorm_ip<<<8192, 256, 0, stream>>>(attn, norm_w);

  gemm256<1><<<32 * 16, 512, 0, stream>>>(Xb, Wg, (void*)gated, attn, 8192, 4096, 4096);
  gemm256<2><<<32 * 16, 512, 0, stream>>>(gated, Wo, d_out, nullptr, 8192, 4096, 4096);
}